// Round 1
// baseline (287.644 us; speedup 1.0000x reference)
//
#include <hip/hip_runtime.h>
#include <cstdint>

// ---------------------------------------------------------------------------
// DefaultAttention: x[4,2048,1024] fp32; k=xWk^T+bk, q=xWq^T+bq, v=xWv^T+bv;
// sim = k q^T / 32 (causal tril), attn = softmax(sim), out = attn @ v (fp32).
// Strategy: f16 MFMA GEMMs (m97 structure: 128x128 tile, BK=32,
// global_load_lds width=16), triangular-tile skipping, shifted exp softmax.
// ---------------------------------------------------------------------------

typedef __attribute__((ext_vector_type(8))) _Float16 f16x8;
typedef __attribute__((ext_vector_type(4))) float f32x4;

__device__ __forceinline__ unsigned short f2h(float x) {
  return __builtin_bit_cast(unsigned short, (_Float16)x);
}
__device__ __forceinline__ float h2f(unsigned short u) {
  return (float)__builtin_bit_cast(_Float16, u);
}

// async global->LDS, 16B per lane; LDS dest = wave-uniform base + lane*16
__device__ __forceinline__ void lds_dma16(const void* g, void* l) {
  auto gp = reinterpret_cast<const __attribute__((address_space(1))) void*>(
      reinterpret_cast<uintptr_t>(g));
  auto lp = reinterpret_cast<__attribute__((address_space(3))) void*>(
      reinterpret_cast<uintptr_t>(l));
  __builtin_amdgcn_global_load_lds(gp, lp, 16, 0, 0);
}

// ---------------------------------------------------------------------------
// Core: C[128x128] += A[128xK] * B[128xK]^T   (both row-major, K contiguous)
// 256 threads = 4 waves, each wave owns a 64x64 quadrant as 4x4 MFMA tiles.
// As/Bs: 128*32 ushort (8KB each), packed [row][32] (no padding: lds_dma).
// ---------------------------------------------------------------------------
__device__ __forceinline__ void gemm128(const unsigned short* __restrict__ Ag,
                                        const unsigned short* __restrict__ Bg,
                                        int lda, int ldb, int nk,
                                        unsigned short* As, unsigned short* Bs,
                                        f32x4 acc[4][4]) {
  const int tid = threadIdx.x;
  const int lane = tid & 63, wave = tid >> 6;
  const int wm = wave >> 1, wn = wave & 1;
  const int sr = lane >> 2;        // staging row within 16-row chunk
  const int sc = (lane & 3) * 8;   // staging col (elements)
  const int rr = lane & 15, qq = lane >> 4;

#pragma unroll
  for (int i = 0; i < 4; ++i)
#pragma unroll
    for (int j = 0; j < 4; ++j) {
      f32x4 z = {0.f, 0.f, 0.f, 0.f};
      acc[i][j] = z;
    }

  for (int k0 = 0; k0 < nk; k0 += 32) {
    // stage A,B tiles: 8 chunks of 1KB each; wave w stages chunks 2w,2w+1
#pragma unroll
    for (int c = 0; c < 2; ++c) {
      int chunk = wave * 2 + c;
      int row = chunk * 16 + sr;
      lds_dma16(Ag + (size_t)row * lda + k0 + sc, As + chunk * 512);
      lds_dma16(Bg + (size_t)row * ldb + k0 + sc, Bs + chunk * 512);
    }
    __syncthreads();  // compiler inserts s_waitcnt vmcnt(0) before barrier

    f16x8 af[4], bf[4];
    const unsigned short* Ar = As + (wm * 64 + rr) * 32 + qq * 8;
    const unsigned short* Br = Bs + (wn * 64 + rr) * 32 + qq * 8;
#pragma unroll
    for (int i = 0; i < 4; ++i) af[i] = *(const f16x8*)(Ar + i * 512);
#pragma unroll
    for (int j = 0; j < 4; ++j) bf[j] = *(const f16x8*)(Br + j * 512);
#pragma unroll
    for (int i = 0; i < 4; ++i)
#pragma unroll
      for (int j = 0; j < 4; ++j)
        acc[i][j] = __builtin_amdgcn_mfma_f32_16x16x32_f16(af[i], bf[j],
                                                           acc[i][j], 0, 0, 0);
    __syncthreads();
  }
}

// ---------------------------------------------------------------------------
// fp32 -> f16 converts
// ---------------------------------------------------------------------------
__global__ void cvt_x_kernel(const float* __restrict__ s,
                             unsigned short* __restrict__ d, int n4) {
  int i = blockIdx.x * blockDim.x + threadIdx.x;
  if (i >= n4) return;
  float4 f = ((const float4*)s)[i];
  ushort4 u;
  u.x = f2h(f.x); u.y = f2h(f.y); u.z = f2h(f.z); u.w = f2h(f.w);
  ((ushort4*)d)[i] = u;
}

__global__ void cvt_w_kernel(const float* __restrict__ w0,
                             const float* __restrict__ w1,
                             const float* __restrict__ w2,
                             unsigned short* __restrict__ d) {
  int z = blockIdx.z;
  const float* s = (z == 0) ? w0 : ((z == 1) ? w1 : w2);
  int i = blockIdx.x * blockDim.x + threadIdx.x;  // 262144 float4s
  float4 f = ((const float4*)s)[i];
  ushort4 u;
  u.x = f2h(f.x); u.y = f2h(f.y); u.z = f2h(f.z); u.w = f2h(f.w);
  ((ushort4*)(d + (size_t)z * 1048576))[i] = u;
}

// ---------------------------------------------------------------------------
// QKV projection: dst[m,f] = sum_e xh[m,e]*W[f,e] + bias[f]   (f16 out)
// grid (8, 64, 3): x = n-tile, y = m-tile, z = which of {k,q,v}
// ---------------------------------------------------------------------------
__global__ __launch_bounds__(256) void qkv_gemm_kernel(
    const unsigned short* __restrict__ xh, const unsigned short* __restrict__ wh,
    const float* __restrict__ bk, const float* __restrict__ bq,
    const float* __restrict__ bv, unsigned short* __restrict__ kh,
    unsigned short* __restrict__ qh, unsigned short* __restrict__ vh) {
  __shared__ unsigned short As[128 * 32], Bs[128 * 32];
  const int z = blockIdx.z;
  const unsigned short* W = wh + (size_t)z * 1048576;
  const float* bias = (z == 0) ? bk : ((z == 1) ? bq : bv);
  unsigned short* dst = (z == 0) ? kh : ((z == 1) ? qh : vh);
  const int tn = blockIdx.x, tm = blockIdx.y;

  f32x4 acc[4][4];
  gemm128(xh + (size_t)tm * 128 * 1024, W + (size_t)tn * 128 * 1024,
          1024, 1024, 1024, As, Bs, acc);

  const int lane = threadIdx.x & 63, wave = threadIdx.x >> 6;
  const int wm = wave >> 1, wn = wave & 1, rr = lane & 15, qq = lane >> 4;
  float bj[4];
#pragma unroll
  for (int j = 0; j < 4; ++j)
    bj[j] = bias[tn * 128 + wn * 64 + j * 16 + rr];
#pragma unroll
  for (int i = 0; i < 4; ++i)
#pragma unroll
    for (int reg = 0; reg < 4; ++reg) {
      int gm = tm * 128 + wm * 64 + i * 16 + qq * 4 + reg;
#pragma unroll
      for (int j = 0; j < 4; ++j) {
        int gc = tn * 128 + wn * 64 + j * 16 + rr;
        dst[(size_t)gm * 1024 + gc] = f2h(acc[i][j][reg] + bj[j]);
      }
    }
}

// ---------------------------------------------------------------------------
// v[b,t,d] -> vT[b,d,t]  (f16)
// ---------------------------------------------------------------------------
__global__ void transpose_v_kernel(const unsigned short* __restrict__ v,
                                   unsigned short* __restrict__ vT) {
  __shared__ unsigned short tile[32][33];
  const int b = blockIdx.z;
  const unsigned short* vp = v + (size_t)b * 2048 * 1024;
  unsigned short* vtp = vT + (size_t)b * 1024 * 2048;
  const int t0 = blockIdx.x * 32, d0 = blockIdx.y * 32;
  const int x = threadIdx.x, y = threadIdx.y;
#pragma unroll
  for (int i = 0; i < 32; i += 8)
    tile[y + i][x] = vp[(size_t)(t0 + y + i) * 1024 + d0 + x];
  __syncthreads();
#pragma unroll
  for (int i = 0; i < 32; i += 8)
    vtp[(size_t)(d0 + y + i) * 2048 + t0 + x] = tile[x][y + i];
}

// ---------------------------------------------------------------------------
// scores: P[b,s,t] = exp(k[s].q[t]/32 - 4) for t<=s else 0   (f16)
// grid (16,16,4); skip strictly-above-diagonal tiles entirely.
// exp shift by 4 cancels in normalization; guards f16 range.
// ---------------------------------------------------------------------------
__global__ __launch_bounds__(256) void scores_kernel(
    const unsigned short* __restrict__ kh, const unsigned short* __restrict__ qh,
    unsigned short* __restrict__ P) {
  const int tt = blockIdx.x, ts = blockIdx.y, b = blockIdx.z;
  if (tt > ts) return;
  __shared__ unsigned short As[128 * 32], Bs[128 * 32];

  f32x4 acc[4][4];
  gemm128(kh + ((size_t)(b * 2048 + ts * 128)) * 1024,
          qh + ((size_t)(b * 2048 + tt * 128)) * 1024,
          1024, 1024, 1024, As, Bs, acc);

  const int lane = threadIdx.x & 63, wave = threadIdx.x >> 6;
  const int wm = wave >> 1, wn = wave & 1, rr = lane & 15, qq = lane >> 4;
  unsigned short* Pb = P + (size_t)b * 2048 * 2048;
#pragma unroll
  for (int i = 0; i < 4; ++i)
#pragma unroll
    for (int reg = 0; reg < 4; ++reg) {
      int srow = ts * 128 + wm * 64 + i * 16 + qq * 4 + reg;
#pragma unroll
      for (int j = 0; j < 4; ++j) {
        int tcol = tt * 128 + wn * 64 + j * 16 + rr;
        float e = (tcol <= srow) ? __expf(acc[i][j][reg] * 0.03125f - 4.0f)
                                 : 0.0f;
        Pb[(size_t)srow * 2048 + tcol] = f2h(e);
      }
    }
}

// ---------------------------------------------------------------------------
// rowsum: rinv[b*2048+s] = 1 / sum_{t<=diag tile} P[b,s,t]; one wave per row
// ---------------------------------------------------------------------------
__global__ __launch_bounds__(256) void rowsum_kernel(
    const unsigned short* __restrict__ P, float* __restrict__ rinv) {
  const int row = blockIdx.x * 4 + (threadIdx.x >> 6);  // 0..8191
  const int lane = threadIdx.x & 63;
  const int s = row & 2047;
  const int len = ((s >> 7) + 1) * 128;  // valid region incl. in-tile zeros
  const unsigned short* Pr = P + (size_t)row * 2048;
  float sum = 0.f;
  for (int t = lane * 8; t < len; t += 512) {
    uint4 u = *(const uint4*)(Pr + t);
    sum += h2f((unsigned short)(u.x & 0xffff)) + h2f((unsigned short)(u.x >> 16));
    sum += h2f((unsigned short)(u.y & 0xffff)) + h2f((unsigned short)(u.y >> 16));
    sum += h2f((unsigned short)(u.z & 0xffff)) + h2f((unsigned short)(u.z >> 16));
    sum += h2f((unsigned short)(u.w & 0xffff)) + h2f((unsigned short)(u.w >> 16));
  }
#pragma unroll
  for (int off = 32; off; off >>= 1) sum += __shfl_xor(sum, off, 64);
  if (lane == 0) rinv[row] = 1.0f / sum;
}

// ---------------------------------------------------------------------------
// out[b,s,d] = rinv[b,s] * sum_t P[b,s,t] * vT[b,d,t]   (fp32 out)
// grid (8,16,4); K truncated to (ts+1)*128 (P==0 beyond).
// blockIdx.y reversed so the K=2048 row-tiles dispatch first (tail balance).
// ---------------------------------------------------------------------------
__global__ __launch_bounds__(256) void pv_gemm_kernel(
    const unsigned short* __restrict__ P, const unsigned short* __restrict__ vT,
    const float* __restrict__ rinv, float* __restrict__ out) {
  const int td = blockIdx.x, ts = 15 - blockIdx.y, b = blockIdx.z;
  __shared__ unsigned short As[128 * 32], Bs[128 * 32];

  f32x4 acc[4][4];
  gemm128(P + ((size_t)(b * 2048 + ts * 128)) * 2048,
          vT + ((size_t)(b * 1024 + td * 128)) * 2048,
          2048, 2048, (ts + 1) * 128, As, Bs, acc);

  const int lane = threadIdx.x & 63, wave = threadIdx.x >> 6;
  const int wm = wave >> 1, wn = wave & 1, rr = lane & 15, qq = lane >> 4;
#pragma unroll
  for (int i = 0; i < 4; ++i)
#pragma unroll
    for (int reg = 0; reg < 4; ++reg) {
      int srow = ts * 128 + wm * 64 + i * 16 + qq * 4 + reg;
      float rv = rinv[b * 2048 + srow];
#pragma unroll
      for (int j = 0; j < 4; ++j) {
        int dcol = td * 128 + wn * 64 + j * 16 + rr;
        out[((size_t)(b * 2048 + srow)) * 1024 + dcol] = acc[i][j][reg] * rv;
      }
    }
}

// ---------------------------------------------------------------------------
// launch
// ---------------------------------------------------------------------------
extern "C" void kernel_launch(void* const* d_in, const int* in_sizes, int n_in,
                              void* d_out, int out_size, void* d_ws,
                              size_t ws_size, hipStream_t stream) {
  const float* x  = (const float*)d_in[0];
  const float* Wk = (const float*)d_in[1];
  const float* bk = (const float*)d_in[2];
  const float* Wq = (const float*)d_in[3];
  const float* bq = (const float*)d_in[4];
  const float* Wv = (const float*)d_in[5];
  const float* bv = (const float*)d_in[6];
  float* out = (float*)d_out;

  char* ws = (char*)d_ws;
  const size_t MB = 1ull << 20;
  // Aliased layout (86 MB total): P overlays xh/wh/vh, which are dead by the
  // time the scores kernel writes P (stream-ordered).
  unsigned short* xh = (unsigned short*)(ws + 0);        // 16 MB  [0,16)
  unsigned short* wh = (unsigned short*)(ws + 16 * MB);  //  6 MB  [16,22)
  unsigned short* vh = (unsigned short*)(ws + 22 * MB);  // 16 MB  [22,38)
  unsigned short* P  = (unsigned short*)(ws + 0);        // 32 MB  [0,32) alias
  unsigned short* kh = (unsigned short*)(ws + 38 * MB);  // 16 MB  [38,54)
  unsigned short* qh = (unsigned short*)(ws + 54 * MB);  // 16 MB  [54,70)
  unsigned short* vT = (unsigned short*)(ws + 70 * MB);  // 16 MB  [70,86)
  float* rinv = (float*)(ws + 86 * MB);                  // 32 KB

  // 1) converts
  cvt_x_kernel<<<8192, 256, 0, stream>>>(x, xh, 8388608 / 4);
  cvt_w_kernel<<<dim3(1024, 1, 3), 256, 0, stream>>>(Wk, Wq, Wv, wh);
  // 2) QKV projections (f16)
  qkv_gemm_kernel<<<dim3(8, 64, 3), 256, 0, stream>>>(xh, wh, bk, bq, bv,
                                                      kh, qh, vh);
  // 3) v -> vT
  transpose_v_kernel<<<dim3(64, 32, 4), dim3(32, 8), 0, stream>>>(vh, vT);
  // 4) masked exp(scores) (lower-triangular tiles only)
  scores_kernel<<<dim3(16, 16, 4), 256, 0, stream>>>(kh, qh, P);
  // 5) softmax denominators
  rowsum_kernel<<<2048, 256, 0, stream>>>(P, rinv);
  // 6) (P @ v) * rinv -> out
  pv_gemm_kernel<<<dim3(8, 16, 4), 256, 0, stream>>>(P, vT, rinv, out);
}

// Round 2
// 277.193 us; speedup vs baseline: 1.0377x; 1.0377x over previous
//
#include <hip/hip_runtime.h>
#include <cstdint>

// ---------------------------------------------------------------------------
// DefaultAttention: x[4,2048,1024] fp32; k=xWk^T+bk, q=xWq^T+bq, v=xWv^T+bv;
// sim = k q^T / 32 (causal tril), attn = softmax(sim), out = attn @ v (fp32).
// R2: qkv grid reorder for L2 reuse (z fast), XOR-swizzled LDS layout
// (bank-conflict-free b128 reads under the lds_dma constraint), rowsum fused
// into scores epilogue via atomics, converts merged.
// ---------------------------------------------------------------------------

typedef __attribute__((ext_vector_type(8))) _Float16 f16x8;
typedef __attribute__((ext_vector_type(4))) float f32x4;

__device__ __forceinline__ unsigned short f2h(float x) {
  return __builtin_bit_cast(unsigned short, (_Float16)x);
}

// async global->LDS, 16B per lane; LDS dest = wave-uniform base + lane*16
__device__ __forceinline__ void lds_dma16(const void* g, void* l) {
  auto gp = reinterpret_cast<const __attribute__((address_space(1))) void*>(
      reinterpret_cast<uintptr_t>(g));
  auto lp = reinterpret_cast<__attribute__((address_space(3))) void*>(
      reinterpret_cast<uintptr_t>(l));
  __builtin_amdgcn_global_load_lds(gp, lp, 16, 0, 0);
}

// ---------------------------------------------------------------------------
// Core: C[128x128] += A[128xK] * B[128xK]^T   (both row-major, K contiguous)
// 256 threads = 4 waves, each wave owns a 64x64 quadrant as 4x4 MFMA tiles.
// As/Bs: 128*32 ushort (8KB each), [row][32] with XOR column swizzle:
// LDS slot (row, s) holds global col-block s ^ ((row>>1)&3). Readers at
// (row, col-block qq) use slot qq ^ ((rr>>1)&3) -> 64 lanes spread 8-per-
// 4-bank-cell = conflict-free minimum for b128.
// ---------------------------------------------------------------------------
__device__ __forceinline__ void gemm128(const unsigned short* __restrict__ Ag,
                                        const unsigned short* __restrict__ Bg,
                                        int lda, int ldb, int nk,
                                        unsigned short* As, unsigned short* Bs,
                                        f32x4 acc[4][4]) {
  const int tid = threadIdx.x;
  const int lane = tid & 63, wave = tid >> 6;
  const int wm = wave >> 1, wn = wave & 1;
  const int sr = lane >> 2;                               // staging row in chunk
  const int scb = (((lane & 3) ^ ((lane >> 3) & 3)) * 8); // swizzled src col
  const int rr = lane & 15, qq = lane >> 4;
  const int slot = ((qq ^ ((rr >> 1) & 3)) * 8);          // swizzled read col

#pragma unroll
  for (int i = 0; i < 4; ++i)
#pragma unroll
    for (int j = 0; j < 4; ++j) {
      f32x4 z = {0.f, 0.f, 0.f, 0.f};
      acc[i][j] = z;
    }

  for (int k0 = 0; k0 < nk; k0 += 32) {
    // stage A,B tiles: 8 chunks of 1KB each; wave w stages chunks 2w,2w+1
#pragma unroll
    for (int c = 0; c < 2; ++c) {
      int chunk = wave * 2 + c;
      int row = chunk * 16 + sr;
      lds_dma16(Ag + (size_t)row * lda + k0 + scb, As + chunk * 512);
      lds_dma16(Bg + (size_t)row * ldb + k0 + scb, Bs + chunk * 512);
    }
    __syncthreads();

    f16x8 af[4], bf[4];
    const unsigned short* Ar = As + (wm * 64 + rr) * 32 + slot;
    const unsigned short* Br = Bs + (wn * 64 + rr) * 32 + slot;
#pragma unroll
    for (int i = 0; i < 4; ++i) af[i] = *(const f16x8*)(Ar + i * 512);
#pragma unroll
    for (int j = 0; j < 4; ++j) bf[j] = *(const f16x8*)(Br + j * 512);
#pragma unroll
    for (int i = 0; i < 4; ++i)
#pragma unroll
      for (int j = 0; j < 4; ++j)
        acc[i][j] = __builtin_amdgcn_mfma_f32_16x16x32_f16(af[i], bf[j],
                                                           acc[i][j], 0, 0, 0);
    __syncthreads();
  }
}

// ---------------------------------------------------------------------------
// fp32 -> f16 convert: x (2097152 float4) then Wk,Wq,Wv (262144 float4 each)
// into contiguous [xh | wh] region of ws.
// ---------------------------------------------------------------------------
__global__ void cvt_kernel(const float* __restrict__ x,
                           const float* __restrict__ w0,
                           const float* __restrict__ w1,
                           const float* __restrict__ w2,
                           unsigned short* __restrict__ dst) {
  int i = blockIdx.x * 256 + threadIdx.x;  // 0 .. 2883583
  const float* s;
  size_t si;
  if (i < 2097152) {
    s = x; si = i;
  } else {
    int j = i - 2097152;
    int z = j >> 18;
    s = (z == 0) ? w0 : ((z == 1) ? w1 : w2);
    si = j & 262143;
  }
  float4 f = ((const float4*)s)[si];
  ushort4 u;
  u.x = f2h(f.x); u.y = f2h(f.y); u.z = f2h(f.z); u.w = f2h(f.w);
  ((ushort4*)dst)[i] = u;
}

// ---------------------------------------------------------------------------
// QKV projection: dst[m,f] = sum_e xh[m,e]*W[f,e] + bias[f]   (f16 out)
// grid (24, 64): x = z*8 + tn  (all 24 blocks sharing an xh m-slab are
// temporally adjacent -> xh slab + all W stay in L2/L3), y = m-tile.
// ---------------------------------------------------------------------------
__global__ __launch_bounds__(256) void qkv_gemm_kernel(
    const unsigned short* __restrict__ xh, const unsigned short* __restrict__ wh,
    const float* __restrict__ bk, const float* __restrict__ bq,
    const float* __restrict__ bv, unsigned short* __restrict__ kh,
    unsigned short* __restrict__ qh, unsigned short* __restrict__ vh) {
  __shared__ unsigned short As[128 * 32], Bs[128 * 32];
  const int tn = blockIdx.x & 7, z = blockIdx.x >> 3;
  const unsigned short* W = wh + (size_t)z * 1048576;
  const float* bias = (z == 0) ? bk : ((z == 1) ? bq : bv);
  unsigned short* dst = (z == 0) ? kh : ((z == 1) ? qh : vh);
  const int tm = blockIdx.y;

  f32x4 acc[4][4];
  gemm128(xh + (size_t)tm * 128 * 1024, W + (size_t)tn * 128 * 1024,
          1024, 1024, 1024, As, Bs, acc);

  const int lane = threadIdx.x & 63, wave = threadIdx.x >> 6;
  const int wm = wave >> 1, wn = wave & 1, rr = lane & 15, qq = lane >> 4;
  float bj[4];
#pragma unroll
  for (int j = 0; j < 4; ++j)
    bj[j] = bias[tn * 128 + wn * 64 + j * 16 + rr];
#pragma unroll
  for (int i = 0; i < 4; ++i)
#pragma unroll
    for (int reg = 0; reg < 4; ++reg) {
      int gm = tm * 128 + wm * 64 + i * 16 + qq * 4 + reg;
#pragma unroll
      for (int j = 0; j < 4; ++j) {
        int gc = tn * 128 + wn * 64 + j * 16 + rr;
        dst[(size_t)gm * 1024 + gc] = f2h(acc[i][j][reg] + bj[j]);
      }
    }
}

// ---------------------------------------------------------------------------
// v[b,t,d] -> vT[b,d,t]  (f16)
// ---------------------------------------------------------------------------
__global__ void transpose_v_kernel(const unsigned short* __restrict__ v,
                                   unsigned short* __restrict__ vT) {
  __shared__ unsigned short tile[32][33];
  const int b = blockIdx.z;
  const unsigned short* vp = v + (size_t)b * 2048 * 1024;
  unsigned short* vtp = vT + (size_t)b * 1024 * 2048;
  const int t0 = blockIdx.x * 32, d0 = blockIdx.y * 32;
  const int x = threadIdx.x, y = threadIdx.y;
#pragma unroll
  for (int i = 0; i < 32; i += 8)
    tile[y + i][x] = vp[(size_t)(t0 + y + i) * 1024 + d0 + x];
  __syncthreads();
#pragma unroll
  for (int i = 0; i < 32; i += 8)
    vtp[(size_t)(d0 + y + i) * 2048 + t0 + x] = tile[x][y + i];
}

// ---------------------------------------------------------------------------
// scores: P[b,s,t] = exp(k[s].q[t]/32 - 4) for t<=s else 0  (f16), and
// rsum[b,s] += per-tile row sums (atomic). Skip above-diagonal tiles.
// ---------------------------------------------------------------------------
__global__ __launch_bounds__(256) void scores_kernel(
    const unsigned short* __restrict__ kh, const unsigned short* __restrict__ qh,
    unsigned short* __restrict__ P, float* __restrict__ rsum) {
  const int tt = blockIdx.x, ts = blockIdx.y, b = blockIdx.z;
  if (tt > ts) return;
  __shared__ unsigned short As[128 * 32], Bs[128 * 32];

  f32x4 acc[4][4];
  gemm128(kh + ((size_t)(b * 2048 + ts * 128)) * 1024,
          qh + ((size_t)(b * 2048 + tt * 128)) * 1024,
          1024, 1024, 1024, As, Bs, acc);

  const int lane = threadIdx.x & 63, wave = threadIdx.x >> 6;
  const int wm = wave >> 1, wn = wave & 1, rr = lane & 15, qq = lane >> 4;
  unsigned short* Pb = P + (size_t)b * 2048 * 2048;
  float* rs = rsum + b * 2048;
#pragma unroll
  for (int i = 0; i < 4; ++i)
#pragma unroll
    for (int reg = 0; reg < 4; ++reg) {
      int srow = ts * 128 + wm * 64 + i * 16 + qq * 4 + reg;
      float p = 0.f;
#pragma unroll
      for (int j = 0; j < 4; ++j) {
        int tcol = tt * 128 + wn * 64 + j * 16 + rr;
        float e = (tcol <= srow) ? __expf(acc[i][j][reg] * 0.03125f - 4.0f)
                                 : 0.0f;
        Pb[(size_t)srow * 2048 + tcol] = f2h(e);
        p += e;
      }
      // reduce over rr lanes (bits 0-3); qq groups stay separate
#pragma unroll
      for (int off = 1; off < 16; off <<= 1) p += __shfl_xor(p, off);
      if (rr == 0) atomicAdd(rs + srow, p);
    }
}

// ---------------------------------------------------------------------------
// out[b,s,d] = (1/rsum[b,s]) * sum_t P[b,s,t] * vT[b,d,t]   (fp32 out)
// grid (8,16,4); K truncated to (ts+1)*128 (P==0 beyond).
// blockIdx.y reversed so the K=2048 row-tiles dispatch first (tail balance).
// ---------------------------------------------------------------------------
__global__ __launch_bounds__(256) void pv_gemm_kernel(
    const unsigned short* __restrict__ P, const unsigned short* __restrict__ vT,
    const float* __restrict__ rsum, float* __restrict__ out) {
  const int td = blockIdx.x, ts = 15 - blockIdx.y, b = blockIdx.z;
  __shared__ unsigned short As[128 * 32], Bs[128 * 32];

  f32x4 acc[4][4];
  gemm128(P + ((size_t)(b * 2048 + ts * 128)) * 2048,
          vT + ((size_t)(b * 1024 + td * 128)) * 2048,
          2048, 2048, (ts + 1) * 128, As, Bs, acc);

  const int lane = threadIdx.x & 63, wave = threadIdx.x >> 6;
  const int wm = wave >> 1, wn = wave & 1, rr = lane & 15, qq = lane >> 4;
#pragma unroll
  for (int i = 0; i < 4; ++i)
#pragma unroll
    for (int reg = 0; reg < 4; ++reg) {
      int srow = ts * 128 + wm * 64 + i * 16 + qq * 4 + reg;
      float rv = __builtin_amdgcn_rcpf(rsum[b * 2048 + srow]);
#pragma unroll
      for (int j = 0; j < 4; ++j) {
        int dcol = td * 128 + wn * 64 + j * 16 + rr;
        out[((size_t)(b * 2048 + srow)) * 1024 + dcol] = acc[i][j][reg] * rv;
      }
    }
}

// ---------------------------------------------------------------------------
// launch
// ---------------------------------------------------------------------------
extern "C" void kernel_launch(void* const* d_in, const int* in_sizes, int n_in,
                              void* d_out, int out_size, void* d_ws,
                              size_t ws_size, hipStream_t stream) {
  const float* x  = (const float*)d_in[0];
  const float* Wk = (const float*)d_in[1];
  const float* bk = (const float*)d_in[2];
  const float* Wq = (const float*)d_in[3];
  const float* bq = (const float*)d_in[4];
  const float* Wv = (const float*)d_in[5];
  const float* bv = (const float*)d_in[6];
  float* out = (float*)d_out;

  char* ws = (char*)d_ws;
  const size_t MB = 1ull << 20;
  // Aliased layout (86 MB + 32 KB): P overlays xh/wh/vh (dead by scores).
  unsigned short* xh = (unsigned short*)(ws + 0);        // 16 MB  [0,16)
  unsigned short* wh = (unsigned short*)(ws + 16 * MB);  //  6 MB  [16,22)
  unsigned short* vh = (unsigned short*)(ws + 22 * MB);  // 16 MB  [22,38)
  unsigned short* P  = (unsigned short*)(ws + 0);        // 32 MB  [0,32) alias
  unsigned short* kh = (unsigned short*)(ws + 38 * MB);  // 16 MB  [38,54)
  unsigned short* qh = (unsigned short*)(ws + 54 * MB);  // 16 MB  [54,70)
  unsigned short* vT = (unsigned short*)(ws + 70 * MB);  // 16 MB  [70,86)
  float* rsum = (float*)(ws + 86 * MB);                  // 32 KB

  hipMemsetAsync(rsum, 0, 8192 * sizeof(float), stream);
  // 1) converts (x + 3 W into contiguous [xh|wh])
  cvt_kernel<<<11264, 256, 0, stream>>>(x, Wk, Wq, Wv, xh);
  // 2) QKV projections (f16); z varies fast for xh L2/L3 reuse
  qkv_gemm_kernel<<<dim3(24, 64), 256, 0, stream>>>(xh, wh, bk, bq, bv,
                                                    kh, qh, vh);
  // 3) v -> vT
  transpose_v_kernel<<<dim3(64, 32, 4), dim3(32, 8), 0, stream>>>(vh, vT);
  // 4) masked exp(scores) + fused row-sum atomics
  scores_kernel<<<dim3(16, 16, 4), 256, 0, stream>>>(kh, qh, P, rsum);
  // 5) (P @ v) * (1/rsum) -> out
  pv_gemm_kernel<<<dim3(8, 16, 4), 256, 0, stream>>>(P, vT, rsum, out);
}

// Round 3
// 266.946 us; speedup vs baseline: 1.0775x; 1.0384x over previous
//
#include <hip/hip_runtime.h>
#include <cstdint>

// ---------------------------------------------------------------------------
// DefaultAttention: x[4,2048,1024] fp32; k=xWk^T+bk, q=xWq^T+bq, v=xWv^T+bv;
// sim = k q^T / 32 (causal tril), attn = softmax(sim), out = attn @ v (fp32).
// R3: BK=64 (half the barrier drains per K; LDS 32KB keeps 5 blocks/CU),
// XOR swizzle adapted to 64-wide rows, vectorized v-transpose, triangular
// scores grid, rsum zero folded into cvt.
// ---------------------------------------------------------------------------

typedef __attribute__((ext_vector_type(8))) _Float16 f16x8;
typedef __attribute__((ext_vector_type(4))) float f32x4;

__device__ __forceinline__ unsigned short f2h(float x) {
  return __builtin_bit_cast(unsigned short, (_Float16)x);
}

// async global->LDS, 16B per lane; LDS dest = wave-uniform base + lane*16
__device__ __forceinline__ void lds_dma16(const void* g, void* l) {
  auto gp = reinterpret_cast<const __attribute__((address_space(1))) void*>(
      reinterpret_cast<uintptr_t>(g));
  auto lp = reinterpret_cast<__attribute__((address_space(3))) void*>(
      reinterpret_cast<uintptr_t>(l));
  __builtin_amdgcn_global_load_lds(gp, lp, 16, 0, 0);
}

// ---------------------------------------------------------------------------
// Core: C[128x128] += A[128xK] * B[128xK]^T   (both row-major, K contiguous)
// BK=64. As/Bs: 128 rows x 64 ush (16KB each). Row stride 128B = 32 banks, so
// un-swizzled column-block reads would be 16-way conflicted; we store source
// col-block cb at LDS slot cb ^ (row&7). b128 reads then spread 64 lanes over
// all 8 slots (8 lanes per 4-bank cell = structural floor, conflict-free).
// Staging: chunk = 8 rows (64 lanes x 16B); lane l -> row l>>3, slot l&7,
// source col-block (l&7) ^ (l>>3).
// ---------------------------------------------------------------------------
__device__ __forceinline__ void gemm128(const unsigned short* __restrict__ Ag,
                                        const unsigned short* __restrict__ Bg,
                                        int lda, int ldb, int nk,
                                        unsigned short* As, unsigned short* Bs,
                                        f32x4 acc[4][4]) {
  const int tid = threadIdx.x;
  const int lane = tid & 63, wave = tid >> 6;
  const int wm = wave >> 1, wn = wave & 1;
  const int sr = lane >> 3;                    // staging row within 8-row chunk
  const int scb = ((lane & 7) ^ sr) * 8;       // swizzled source col (ush)
  const int rr = lane & 15, qq = lane >> 4;
  const int slot0 = ((qq) ^ (rr & 7)) * 8;     // k-half 0 read col (ush)
  const int slot1 = ((4 + qq) ^ (rr & 7)) * 8; // k-half 1 read col (ush)

#pragma unroll
  for (int i = 0; i < 4; ++i)
#pragma unroll
    for (int j = 0; j < 4; ++j) {
      f32x4 z = {0.f, 0.f, 0.f, 0.f};
      acc[i][j] = z;
    }

  for (int k0 = 0; k0 < nk; k0 += 64) {
    // 16 chunks of 8 rows; wave w stages chunks 4w..4w+3 (A and B)
#pragma unroll
    for (int c = 0; c < 4; ++c) {
      int chunk = wave * 4 + c;
      int row = chunk * 8 + sr;
      lds_dma16(Ag + (size_t)row * lda + k0 + scb, As + chunk * 512);
      lds_dma16(Bg + (size_t)row * ldb + k0 + scb, Bs + chunk * 512);
    }
    __syncthreads();

    const unsigned short* Ar = As + (wm * 64 + rr) * 64;
    const unsigned short* Br = Bs + (wn * 64 + rr) * 64;
    {
      f16x8 af[4], bf[4];
#pragma unroll
      for (int i = 0; i < 4; ++i) af[i] = *(const f16x8*)(Ar + i * 1024 + slot0);
#pragma unroll
      for (int j = 0; j < 4; ++j) bf[j] = *(const f16x8*)(Br + j * 1024 + slot0);
#pragma unroll
      for (int i = 0; i < 4; ++i)
#pragma unroll
        for (int j = 0; j < 4; ++j)
          acc[i][j] = __builtin_amdgcn_mfma_f32_16x16x32_f16(af[i], bf[j],
                                                             acc[i][j], 0, 0, 0);
    }
    {
      f16x8 af[4], bf[4];
#pragma unroll
      for (int i = 0; i < 4; ++i) af[i] = *(const f16x8*)(Ar + i * 1024 + slot1);
#pragma unroll
      for (int j = 0; j < 4; ++j) bf[j] = *(const f16x8*)(Br + j * 1024 + slot1);
#pragma unroll
      for (int i = 0; i < 4; ++i)
#pragma unroll
        for (int j = 0; j < 4; ++j)
          acc[i][j] = __builtin_amdgcn_mfma_f32_16x16x32_f16(af[i], bf[j],
                                                             acc[i][j], 0, 0, 0);
    }
    __syncthreads();
  }
}

// ---------------------------------------------------------------------------
// fp32 -> f16 convert: x (2097152 float4) then Wk,Wq,Wv (262144 float4 each)
// into contiguous [xh | wh]; last 8 blocks zero rsum (8192 floats).
// ---------------------------------------------------------------------------
__global__ void cvt_kernel(const float* __restrict__ x,
                           const float* __restrict__ w0,
                           const float* __restrict__ w1,
                           const float* __restrict__ w2,
                           unsigned short* __restrict__ dst,
                           float* __restrict__ rsum) {
  int i = blockIdx.x * 256 + threadIdx.x;
  if (i >= 2883584) {  // rsum zero blocks
    int z2 = i - 2883584;
    float4 z = {0.f, 0.f, 0.f, 0.f};
    ((float4*)rsum)[z2] = z;
    return;
  }
  const float* s;
  size_t si;
  if (i < 2097152) {
    s = x; si = i;
  } else {
    int j = i - 2097152;
    int z = j >> 18;
    s = (z == 0) ? w0 : ((z == 1) ? w1 : w2);
    si = j & 262143;
  }
  float4 f = ((const float4*)s)[si];
  ushort4 u;
  u.x = f2h(f.x); u.y = f2h(f.y); u.z = f2h(f.z); u.w = f2h(f.w);
  ((ushort4*)dst)[i] = u;
}

// ---------------------------------------------------------------------------
// QKV projection: dst[m,f] = sum_e xh[m,e]*W[f,e] + bias[f]   (f16 out)
// grid (24, 64): x = z*8 + tn (z fast -> xh slab reused across all 24).
// ---------------------------------------------------------------------------
__global__ __launch_bounds__(256) void qkv_gemm_kernel(
    const unsigned short* __restrict__ xh, const unsigned short* __restrict__ wh,
    const float* __restrict__ bk, const float* __restrict__ bq,
    const float* __restrict__ bv, unsigned short* __restrict__ kh,
    unsigned short* __restrict__ qh, unsigned short* __restrict__ vh) {
  __shared__ unsigned short As[128 * 64], Bs[128 * 64];
  const int tn = blockIdx.x & 7, z = blockIdx.x >> 3;
  const unsigned short* W = wh + (size_t)z * 1048576;
  const float* bias = (z == 0) ? bk : ((z == 1) ? bq : bv);
  unsigned short* dst = (z == 0) ? kh : ((z == 1) ? qh : vh);
  const int tm = blockIdx.y;

  f32x4 acc[4][4];
  gemm128(xh + (size_t)tm * 128 * 1024, W + (size_t)tn * 128 * 1024,
          1024, 1024, 1024, As, Bs, acc);

  const int lane = threadIdx.x & 63, wave = threadIdx.x >> 6;
  const int wm = wave >> 1, wn = wave & 1, rr = lane & 15, qq = lane >> 4;
  float bj[4];
#pragma unroll
  for (int j = 0; j < 4; ++j)
    bj[j] = bias[tn * 128 + wn * 64 + j * 16 + rr];
#pragma unroll
  for (int i = 0; i < 4; ++i)
#pragma unroll
    for (int reg = 0; reg < 4; ++reg) {
      int gm = tm * 128 + wm * 64 + i * 16 + qq * 4 + reg;
#pragma unroll
      for (int j = 0; j < 4; ++j) {
        int gc = tn * 128 + wn * 64 + j * 16 + rr;
        dst[(size_t)gm * 1024 + gc] = f2h(acc[i][j][reg] + bj[j]);
      }
    }
}

// ---------------------------------------------------------------------------
// v[b,t,d] -> vT[b,d,t]  (f16), 64x64 tiles, ushort4 vectorized
// ---------------------------------------------------------------------------
__global__ __launch_bounds__(256) void transpose_v_kernel(
    const unsigned short* __restrict__ v, unsigned short* __restrict__ vT) {
  __shared__ unsigned short tile[64][65];
  const int b = blockIdx.z;
  const unsigned short* vp = v + (size_t)b * 2048 * 1024;
  unsigned short* vtp = vT + (size_t)b * 1024 * 2048;
  const int t0 = blockIdx.x * 64, d0 = blockIdx.y * 64;
  const int lr = threadIdx.x >> 4, lc = (threadIdx.x & 15) * 4;
#pragma unroll
  for (int p = 0; p < 4; ++p) {
    int tr = p * 16 + lr;
    ushort4 u = *(const ushort4*)(vp + (size_t)(t0 + tr) * 1024 + d0 + lc);
    tile[tr][lc] = u.x; tile[tr][lc + 1] = u.y;
    tile[tr][lc + 2] = u.z; tile[tr][lc + 3] = u.w;
  }
  __syncthreads();
#pragma unroll
  for (int p = 0; p < 4; ++p) {
    int dr = p * 16 + lr;
    ushort4 u;
    u.x = tile[lc][dr]; u.y = tile[lc + 1][dr];
    u.z = tile[lc + 2][dr]; u.w = tile[lc + 3][dr];
    *(ushort4*)(vtp + (size_t)(d0 + dr) * 2048 + t0 + lc) = u;
  }
}

// ---------------------------------------------------------------------------
// scores: P[b,s,t] = exp(k[s].q[t]/32 - 4) for t<=s else 0  (f16), plus
// fused row-sum atomics. 1-D triangular grid (136 tiles), y = batch.
// ---------------------------------------------------------------------------
__global__ __launch_bounds__(256) void scores_kernel(
    const unsigned short* __restrict__ kh, const unsigned short* __restrict__ qh,
    unsigned short* __restrict__ P, float* __restrict__ rsum) {
  const int b = blockIdx.y;
  int idx = blockIdx.x;
  int ts = (int)((sqrtf(8.0f * idx + 1.0f) - 1.0f) * 0.5f);
  while ((ts + 1) * (ts + 2) / 2 <= idx) ++ts;
  while (ts * (ts + 1) / 2 > idx) --ts;
  const int tt = idx - ts * (ts + 1) / 2;
  __shared__ unsigned short As[128 * 64], Bs[128 * 64];

  f32x4 acc[4][4];
  gemm128(kh + ((size_t)(b * 2048 + ts * 128)) * 1024,
          qh + ((size_t)(b * 2048 + tt * 128)) * 1024,
          1024, 1024, 1024, As, Bs, acc);

  const int lane = threadIdx.x & 63, wave = threadIdx.x >> 6;
  const int wm = wave >> 1, wn = wave & 1, rr = lane & 15, qq = lane >> 4;
  unsigned short* Pb = P + (size_t)b * 2048 * 2048;
  float* rs = rsum + b * 2048;
#pragma unroll
  for (int i = 0; i < 4; ++i)
#pragma unroll
    for (int reg = 0; reg < 4; ++reg) {
      int srow = ts * 128 + wm * 64 + i * 16 + qq * 4 + reg;
      float p = 0.f;
#pragma unroll
      for (int j = 0; j < 4; ++j) {
        int tcol = tt * 128 + wn * 64 + j * 16 + rr;
        float e = (tcol <= srow) ? __expf(acc[i][j][reg] * 0.03125f - 4.0f)
                                 : 0.0f;
        Pb[(size_t)srow * 2048 + tcol] = f2h(e);
        p += e;
      }
#pragma unroll
      for (int off = 1; off < 16; off <<= 1) p += __shfl_xor(p, off);
      if (rr == 0) atomicAdd(rs + srow, p);
    }
}

// ---------------------------------------------------------------------------
// out[b,s,d] = (1/rsum[b,s]) * sum_t P[b,s,t] * vT[b,d,t]   (fp32 out)
// grid (8,16,4); K truncated to (ts+1)*128; y reversed (big-K first).
// ---------------------------------------------------------------------------
__global__ __launch_bounds__(256) void pv_gemm_kernel(
    const unsigned short* __restrict__ P, const unsigned short* __restrict__ vT,
    const float* __restrict__ rsum, float* __restrict__ out) {
  const int td = blockIdx.x, ts = 15 - blockIdx.y, b = blockIdx.z;
  __shared__ unsigned short As[128 * 64], Bs[128 * 64];

  f32x4 acc[4][4];
  gemm128(P + ((size_t)(b * 2048 + ts * 128)) * 2048,
          vT + ((size_t)(b * 1024 + td * 128)) * 2048,
          2048, 2048, (ts + 1) * 128, As, Bs, acc);

  const int lane = threadIdx.x & 63, wave = threadIdx.x >> 6;
  const int wm = wave >> 1, wn = wave & 1, rr = lane & 15, qq = lane >> 4;
#pragma unroll
  for (int i = 0; i < 4; ++i)
#pragma unroll
    for (int reg = 0; reg < 4; ++reg) {
      int srow = ts * 128 + wm * 64 + i * 16 + qq * 4 + reg;
      float rv = __builtin_amdgcn_rcpf(rsum[b * 2048 + srow]);
#pragma unroll
      for (int j = 0; j < 4; ++j) {
        int dcol = td * 128 + wn * 64 + j * 16 + rr;
        out[((size_t)(b * 2048 + srow)) * 1024 + dcol] = acc[i][j][reg] * rv;
      }
    }
}

// ---------------------------------------------------------------------------
// launch
// ---------------------------------------------------------------------------
extern "C" void kernel_launch(void* const* d_in, const int* in_sizes, int n_in,
                              void* d_out, int out_size, void* d_ws,
                              size_t ws_size, hipStream_t stream) {
  const float* x  = (const float*)d_in[0];
  const float* Wk = (const float*)d_in[1];
  const float* bk = (const float*)d_in[2];
  const float* Wq = (const float*)d_in[3];
  const float* bq = (const float*)d_in[4];
  const float* Wv = (const float*)d_in[5];
  const float* bv = (const float*)d_in[6];
  float* out = (float*)d_out;

  char* ws = (char*)d_ws;
  const size_t MB = 1ull << 20;
  // Aliased layout (86 MB + 32 KB): P overlays xh/wh/vh (dead by scores).
  unsigned short* xh = (unsigned short*)(ws + 0);        // 16 MB  [0,16)
  unsigned short* wh = (unsigned short*)(ws + 16 * MB);  //  6 MB  [16,22)
  unsigned short* vh = (unsigned short*)(ws + 22 * MB);  // 16 MB  [22,38)
  unsigned short* P  = (unsigned short*)(ws + 0);        // 32 MB  [0,32) alias
  unsigned short* kh = (unsigned short*)(ws + 38 * MB);  // 16 MB  [38,54)
  unsigned short* qh = (unsigned short*)(ws + 54 * MB);  // 16 MB  [54,70)
  unsigned short* vT = (unsigned short*)(ws + 70 * MB);  // 16 MB  [70,86)
  float* rsum = (float*)(ws + 86 * MB);                  // 32 KB

  // 1) converts (x + 3 W) + rsum zero-init (last 8 blocks)
  cvt_kernel<<<11272, 256, 0, stream>>>(x, Wk, Wq, Wv, xh, rsum);
  // 2) QKV projections (f16)
  qkv_gemm_kernel<<<dim3(24, 64), 256, 0, stream>>>(xh, wh, bk, bq, bv,
                                                    kh, qh, vh);
  // 3) v -> vT (vectorized)
  transpose_v_kernel<<<dim3(32, 16, 4), 256, 0, stream>>>(vh, vT);
  // 4) masked exp(scores) + fused row-sum atomics (triangular grid)
  scores_kernel<<<dim3(136, 4), 256, 0, stream>>>(kh, qh, P, rsum);
  // 5) (P @ v) * (1/rsum) -> out
  pv_gemm_kernel<<<dim3(8, 16, 4), 256, 0, stream>>>(P, vT, rsum, out);
}

// Round 4
// 250.641 us; speedup vs baseline: 1.1476x; 1.0651x over previous
//
#include <hip/hip_runtime.h>
#include <cstdint>

// ---------------------------------------------------------------------------
// DefaultAttention: x[4,2048,1024] fp32; k=xWk^T+bk, q=xWq^T+bq, v=xWv^T+bv;
// sim = k q^T / 32 (causal tril), attn = softmax(sim), out = attn @ v (fp32).
// R4: BK=32 again (R3's BK=64 regressed: occupancy cliff), but K-loop
// restructured to single-barrier double-buffered pipeline -> staging overlaps
// compute WITHIN a block (critical for scores/pv at ~2 blocks/CU).
// ---------------------------------------------------------------------------

typedef __attribute__((ext_vector_type(8))) _Float16 f16x8;
typedef __attribute__((ext_vector_type(4))) float f32x4;

__device__ __forceinline__ unsigned short f2h(float x) {
  return __builtin_bit_cast(unsigned short, (_Float16)x);
}

// async global->LDS, 16B per lane; LDS dest = wave-uniform base + lane*16
__device__ __forceinline__ void lds_dma16(const void* g, void* l) {
  auto gp = reinterpret_cast<const __attribute__((address_space(1))) void*>(
      reinterpret_cast<uintptr_t>(g));
  auto lp = reinterpret_cast<__attribute__((address_space(3))) void*>(
      reinterpret_cast<uintptr_t>(l));
  __builtin_amdgcn_global_load_lds(gp, lp, 16, 0, 0);
}

// ---------------------------------------------------------------------------
// Core: C[128x128] += A[128xK] * B[128xK]^T  (row-major, K contiguous).
// BK=32, XOR-swizzled [row][32] LDS layout (conflict-free, lds_dma friendly).
// Double-buffered single-barrier pipeline:
//   stage(buf0); for k: { barrier; stage(buf^1,k+32); mfma(buf); buf^=1; }
// The vmcnt(0) drain at each barrier covers loads issued one full compute
// phase earlier. Buffer written at iter i was last read at iter i-1; the
// barrier at iter i start separates those (reads land in regs pre-barrier).
// ---------------------------------------------------------------------------
__device__ __forceinline__ void gemm128(const unsigned short* __restrict__ Ag,
                                        const unsigned short* __restrict__ Bg,
                                        int lda, int ldb, int nk,
                                        unsigned short* As, unsigned short* Bs,
                                        f32x4 acc[4][4]) {
  const int tid = threadIdx.x;
  const int lane = tid & 63, wave = tid >> 6;
  const int wm = wave >> 1, wn = wave & 1;
  const int sr = lane >> 2;                               // staging row in chunk
  const int scb = (((lane & 3) ^ ((lane >> 3) & 3)) * 8); // swizzled src col
  const int rr = lane & 15, qq = lane >> 4;
  const int slot = ((qq ^ ((rr >> 1) & 3)) * 8);          // swizzled read col

#pragma unroll
  for (int i = 0; i < 4; ++i)
#pragma unroll
    for (int j = 0; j < 4; ++j) {
      f32x4 z = {0.f, 0.f, 0.f, 0.f};
      acc[i][j] = z;
    }

  // chunk = 16 rows staged by one wave-quarter pattern; wave w owns 2w,2w+1
  const int srow_a = (wave * 2) * 16 + sr;       // chunk rows for c=0
  // prologue: stage k0=0 into buf 0
#pragma unroll
  for (int c = 0; c < 2; ++c) {
    int chunk = wave * 2 + c;
    int row = chunk * 16 + sr;
    lds_dma16(Ag + (size_t)row * lda + scb, As + chunk * 512);
    lds_dma16(Bg + (size_t)row * ldb + scb, Bs + chunk * 512);
  }
  (void)srow_a;

  int buf = 0;
  for (int k0 = 0; k0 < nk; k0 += 32) {
    __syncthreads();  // drains staging issued one compute-phase ago
    const int kn = k0 + 32;
    if (kn < nk) {
      unsigned short* An = As + (buf ^ 1) * 4096;
      unsigned short* Bn = Bs + (buf ^ 1) * 4096;
#pragma unroll
      for (int c = 0; c < 2; ++c) {
        int chunk = wave * 2 + c;
        int row = chunk * 16 + sr;
        lds_dma16(Ag + (size_t)row * lda + kn + scb, An + chunk * 512);
        lds_dma16(Bg + (size_t)row * ldb + kn + scb, Bn + chunk * 512);
      }
    }

    f16x8 af[4], bf[4];
    const unsigned short* Ar = As + buf * 4096 + (wm * 64 + rr) * 32 + slot;
    const unsigned short* Br = Bs + buf * 4096 + (wn * 64 + rr) * 32 + slot;
#pragma unroll
    for (int i = 0; i < 4; ++i) af[i] = *(const f16x8*)(Ar + i * 512);
#pragma unroll
    for (int j = 0; j < 4; ++j) bf[j] = *(const f16x8*)(Br + j * 512);
#pragma unroll
    for (int i = 0; i < 4; ++i)
#pragma unroll
      for (int j = 0; j < 4; ++j)
        acc[i][j] = __builtin_amdgcn_mfma_f32_16x16x32_f16(af[i], bf[j],
                                                           acc[i][j], 0, 0, 0);
    buf ^= 1;
  }
}

// ---------------------------------------------------------------------------
// fp32 -> f16 convert: x (2097152 float4) then Wk,Wq,Wv (262144 float4 each)
// into contiguous [xh | wh]; last 8 blocks zero rsum (8192 floats).
// ---------------------------------------------------------------------------
__global__ void cvt_kernel(const float* __restrict__ x,
                           const float* __restrict__ w0,
                           const float* __restrict__ w1,
                           const float* __restrict__ w2,
                           unsigned short* __restrict__ dst,
                           float* __restrict__ rsum) {
  int i = blockIdx.x * 256 + threadIdx.x;
  if (i >= 2883584) {  // rsum zero blocks
    int z2 = i - 2883584;
    float4 z = {0.f, 0.f, 0.f, 0.f};
    ((float4*)rsum)[z2] = z;
    return;
  }
  const float* s;
  size_t si;
  if (i < 2097152) {
    s = x; si = i;
  } else {
    int j = i - 2097152;
    int z = j >> 18;
    s = (z == 0) ? w0 : ((z == 1) ? w1 : w2);
    si = j & 262143;
  }
  float4 f = ((const float4*)s)[si];
  ushort4 u;
  u.x = f2h(f.x); u.y = f2h(f.y); u.z = f2h(f.z); u.w = f2h(f.w);
  ((ushort4*)dst)[i] = u;
}

// ---------------------------------------------------------------------------
// QKV projection: dst[m,f] = sum_e xh[m,e]*W[f,e] + bias[f]   (f16 out)
// grid (24, 64): x = z*8 + tn (z fast -> xh slab reused across all 24).
// ---------------------------------------------------------------------------
__global__ __launch_bounds__(256) void qkv_gemm_kernel(
    const unsigned short* __restrict__ xh, const unsigned short* __restrict__ wh,
    const float* __restrict__ bk, const float* __restrict__ bq,
    const float* __restrict__ bv, unsigned short* __restrict__ kh,
    unsigned short* __restrict__ qh, unsigned short* __restrict__ vh) {
  __shared__ unsigned short As[2 * 128 * 32], Bs[2 * 128 * 32];
  const int tn = blockIdx.x & 7, z = blockIdx.x >> 3;
  const unsigned short* W = wh + (size_t)z * 1048576;
  const float* bias = (z == 0) ? bk : ((z == 1) ? bq : bv);
  unsigned short* dst = (z == 0) ? kh : ((z == 1) ? qh : vh);
  const int tm = blockIdx.y;

  f32x4 acc[4][4];
  gemm128(xh + (size_t)tm * 128 * 1024, W + (size_t)tn * 128 * 1024,
          1024, 1024, 1024, As, Bs, acc);

  const int lane = threadIdx.x & 63, wave = threadIdx.x >> 6;
  const int wm = wave >> 1, wn = wave & 1, rr = lane & 15, qq = lane >> 4;
  float bj[4];
#pragma unroll
  for (int j = 0; j < 4; ++j)
    bj[j] = bias[tn * 128 + wn * 64 + j * 16 + rr];
#pragma unroll
  for (int i = 0; i < 4; ++i)
#pragma unroll
    for (int reg = 0; reg < 4; ++reg) {
      int gm = tm * 128 + wm * 64 + i * 16 + qq * 4 + reg;
#pragma unroll
      for (int j = 0; j < 4; ++j) {
        int gc = tn * 128 + wn * 64 + j * 16 + rr;
        dst[(size_t)gm * 1024 + gc] = f2h(acc[i][j][reg] + bj[j]);
      }
    }
}

// ---------------------------------------------------------------------------
// v[b,t,d] -> vT[b,d,t]  (f16), 64x64 tiles, ushort4 vectorized
// ---------------------------------------------------------------------------
__global__ __launch_bounds__(256) void transpose_v_kernel(
    const unsigned short* __restrict__ v, unsigned short* __restrict__ vT) {
  __shared__ unsigned short tile[64][65];
  const int b = blockIdx.z;
  const unsigned short* vp = v + (size_t)b * 2048 * 1024;
  unsigned short* vtp = vT + (size_t)b * 1024 * 2048;
  const int t0 = blockIdx.x * 64, d0 = blockIdx.y * 64;
  const int lr = threadIdx.x >> 4, lc = (threadIdx.x & 15) * 4;
#pragma unroll
  for (int p = 0; p < 4; ++p) {
    int tr = p * 16 + lr;
    ushort4 u = *(const ushort4*)(vp + (size_t)(t0 + tr) * 1024 + d0 + lc);
    tile[tr][lc] = u.x; tile[tr][lc + 1] = u.y;
    tile[tr][lc + 2] = u.z; tile[tr][lc + 3] = u.w;
  }
  __syncthreads();
#pragma unroll
  for (int p = 0; p < 4; ++p) {
    int dr = p * 16 + lr;
    ushort4 u;
    u.x = tile[lc][dr]; u.y = tile[lc + 1][dr];
    u.z = tile[lc + 2][dr]; u.w = tile[lc + 3][dr];
    *(ushort4*)(vtp + (size_t)(d0 + dr) * 2048 + t0 + lc) = u;
  }
}

// ---------------------------------------------------------------------------
// scores: P[b,s,t] = exp(k[s].q[t]/32 - 4) for t<=s else 0  (f16), plus
// fused row-sum atomics. 1-D triangular grid (136 tiles), y = batch.
// ---------------------------------------------------------------------------
__global__ __launch_bounds__(256) void scores_kernel(
    const unsigned short* __restrict__ kh, const unsigned short* __restrict__ qh,
    unsigned short* __restrict__ P, float* __restrict__ rsum) {
  const int b = blockIdx.y;
  int idx = blockIdx.x;
  int ts = (int)((sqrtf(8.0f * idx + 1.0f) - 1.0f) * 0.5f);
  while ((ts + 1) * (ts + 2) / 2 <= idx) ++ts;
  while (ts * (ts + 1) / 2 > idx) --ts;
  const int tt = idx - ts * (ts + 1) / 2;
  __shared__ unsigned short As[2 * 128 * 32], Bs[2 * 128 * 32];

  f32x4 acc[4][4];
  gemm128(kh + ((size_t)(b * 2048 + ts * 128)) * 1024,
          qh + ((size_t)(b * 2048 + tt * 128)) * 1024,
          1024, 1024, 1024, As, Bs, acc);

  const int lane = threadIdx.x & 63, wave = threadIdx.x >> 6;
  const int wm = wave >> 1, wn = wave & 1, rr = lane & 15, qq = lane >> 4;
  unsigned short* Pb = P + (size_t)b * 2048 * 2048;
  float* rs = rsum + b * 2048;
#pragma unroll
  for (int i = 0; i < 4; ++i)
#pragma unroll
    for (int reg = 0; reg < 4; ++reg) {
      int srow = ts * 128 + wm * 64 + i * 16 + qq * 4 + reg;
      float p = 0.f;
#pragma unroll
      for (int j = 0; j < 4; ++j) {
        int tcol = tt * 128 + wn * 64 + j * 16 + rr;
        float e = (tcol <= srow) ? __expf(acc[i][j][reg] * 0.03125f - 4.0f)
                                 : 0.0f;
        Pb[(size_t)srow * 2048 + tcol] = f2h(e);
        p += e;
      }
#pragma unroll
      for (int off = 1; off < 16; off <<= 1) p += __shfl_xor(p, off);
      if (rr == 0) atomicAdd(rs + srow, p);
    }
}

// ---------------------------------------------------------------------------
// out[b,s,d] = (1/rsum[b,s]) * sum_t P[b,s,t] * vT[b,d,t]   (fp32 out)
// grid (8,16,4); K truncated to (ts+1)*128; y reversed (big-K first).
// ---------------------------------------------------------------------------
__global__ __launch_bounds__(256) void pv_gemm_kernel(
    const unsigned short* __restrict__ P, const unsigned short* __restrict__ vT,
    const float* __restrict__ rsum, float* __restrict__ out) {
  const int td = blockIdx.x, ts = 15 - blockIdx.y, b = blockIdx.z;
  __shared__ unsigned short As[2 * 128 * 32], Bs[2 * 128 * 32];

  f32x4 acc[4][4];
  gemm128(P + ((size_t)(b * 2048 + ts * 128)) * 2048,
          vT + ((size_t)(b * 1024 + td * 128)) * 2048,
          2048, 2048, (ts + 1) * 128, As, Bs, acc);

  const int lane = threadIdx.x & 63, wave = threadIdx.x >> 6;
  const int wm = wave >> 1, wn = wave & 1, rr = lane & 15, qq = lane >> 4;
#pragma unroll
  for (int i = 0; i < 4; ++i)
#pragma unroll
    for (int reg = 0; reg < 4; ++reg) {
      int srow = ts * 128 + wm * 64 + i * 16 + qq * 4 + reg;
      float rv = __builtin_amdgcn_rcpf(rsum[b * 2048 + srow]);
#pragma unroll
      for (int j = 0; j < 4; ++j) {
        int dcol = td * 128 + wn * 64 + j * 16 + rr;
        out[((size_t)(b * 2048 + srow)) * 1024 + dcol] = acc[i][j][reg] * rv;
      }
    }
}

// ---------------------------------------------------------------------------
// launch
// ---------------------------------------------------------------------------
extern "C" void kernel_launch(void* const* d_in, const int* in_sizes, int n_in,
                              void* d_out, int out_size, void* d_ws,
                              size_t ws_size, hipStream_t stream) {
  const float* x  = (const float*)d_in[0];
  const float* Wk = (const float*)d_in[1];
  const float* bk = (const float*)d_in[2];
  const float* Wq = (const float*)d_in[3];
  const float* bq = (const float*)d_in[4];
  const float* Wv = (const float*)d_in[5];
  const float* bv = (const float*)d_in[6];
  float* out = (float*)d_out;

  char* ws = (char*)d_ws;
  const size_t MB = 1ull << 20;
  // Aliased layout (86 MB + 32 KB): P overlays xh/wh/vh (dead by scores).
  unsigned short* xh = (unsigned short*)(ws + 0);        // 16 MB  [0,16)
  unsigned short* wh = (unsigned short*)(ws + 16 * MB);  //  6 MB  [16,22)
  unsigned short* vh = (unsigned short*)(ws + 22 * MB);  // 16 MB  [22,38)
  unsigned short* P  = (unsigned short*)(ws + 0);        // 32 MB  [0,32) alias
  unsigned short* kh = (unsigned short*)(ws + 38 * MB);  // 16 MB  [38,54)
  unsigned short* qh = (unsigned short*)(ws + 54 * MB);  // 16 MB  [54,70)
  unsigned short* vT = (unsigned short*)(ws + 70 * MB);  // 16 MB  [70,86)
  float* rsum = (float*)(ws + 86 * MB);                  // 32 KB

  // 1) converts (x + 3 W) + rsum zero-init (last 8 blocks)
  cvt_kernel<<<11272, 256, 0, stream>>>(x, Wk, Wq, Wv, xh, rsum);
  // 2) QKV projections (f16)
  qkv_gemm_kernel<<<dim3(24, 64), 256, 0, stream>>>(xh, wh, bk, bq, bv,
                                                    kh, qh, vh);
  // 3) v -> vT (vectorized)
  transpose_v_kernel<<<dim3(32, 16, 4), 256, 0, stream>>>(vh, vT);
  // 4) masked exp(scores) + fused row-sum atomics (triangular grid)
  scores_kernel<<<dim3(136, 4), 256, 0, stream>>>(kh, qh, P, rsum);
  // 5) (P @ v) * (1/rsum) -> out
  pv_gemm_kernel<<<dim3(8, 16, 4), 256, 0, stream>>>(P, vT, rsum, out);
}